// Round 1
// 299.189 us; speedup vs baseline: 1.0850x; 1.0850x over previous
//
#include <hip/hip_runtime.h>

#define NBINS 512

// ws layout (floats): [0:512) = per-bin column sums, [512:768) = weighted-add accumulator slots
__global__ void init_ws_kernel(float* __restrict__ ws, int n) {
    int t = blockIdx.x * blockDim.x + threadIdx.x;
    if (t < n) ws[t] = 0.0f;
}

// One block (256 threads = 4 waves) per batch row b.
// Wave w handles neighbors k = 4w..4w+3 (one float4 broadcast load of y).
// No LDS staging: each wave reads the base row directly; the 4x intra-block
// reuse is served by L1 (row is 2 KB). Each thread keeps 10 float4 loads in
// flight (2 base + 8 gather) for latency hiding; 256-thread blocks give
// ~8 blocks/CU vs 2 for the old 1024-thread version.
__global__ __launch_bounds__(256) void main_kernel(
        const float* __restrict__ outputs,
        const float* __restrict__ y,
        const float* __restrict__ weights,
        float* __restrict__ out,          // d_out: [cost, diff, bnorm, booster(B)]
        float* __restrict__ accum,        // 256 slots
        int K) {
    __shared__ float s_add[16];

    const int b = blockIdx.x;
    const int t = threadIdx.x;
    const int w = t >> 6;        // wave id, 0..3
    const int lane = t & 63;

    // 4 neighbor indices for this wave (y >= 0, trunc == int cast)
    const float4 yv = ((const float4*)(y + (size_t)b * K))[w];
    const int nn0 = (int)yv.x;
    const int nn1 = (int)yv.y;
    const int nn2 = (int)yv.z;
    const int nn3 = (int)yv.w;

    const float4* bp = (const float4*)(outputs + (size_t)b * NBINS);
    const float4* r0 = (const float4*)(outputs + (size_t)nn0 * NBINS);
    const float4* r1 = (const float4*)(outputs + (size_t)nn1 * NBINS);
    const float4* r2 = (const float4*)(outputs + (size_t)nn2 * NBINS);
    const float4* r3 = (const float4*)(outputs + (size_t)nn3 * NBINS);

    const int i0 = lane * 2;
    const int i1 = lane * 2 + 1;

    // Issue all loads up front; compute afterwards.
    float4 base0 = bp[i0], base1 = bp[i1];
    float4 a0 = r0[i0], a1 = r0[i1];
    float4 c0 = r1[i0], c1 = r1[i1];
    float4 d0 = r2[i0], d1 = r2[i1];
    float4 e0 = r3[i0], e1 = r3[i1];

    float m0 = fmaxf(fmaxf(fmaxf(a0.x + base0.x, a0.y + base0.y),
                           fmaxf(a0.z + base0.z, a0.w + base0.w)),
                     fmaxf(fmaxf(a1.x + base1.x, a1.y + base1.y),
                           fmaxf(a1.z + base1.z, a1.w + base1.w)));
    float m1 = fmaxf(fmaxf(fmaxf(c0.x + base0.x, c0.y + base0.y),
                           fmaxf(c0.z + base0.z, c0.w + base0.w)),
                     fmaxf(fmaxf(c1.x + base1.x, c1.y + base1.y),
                           fmaxf(c1.z + base1.z, c1.w + base1.w)));
    float m2 = fmaxf(fmaxf(fmaxf(d0.x + base0.x, d0.y + base0.y),
                           fmaxf(d0.z + base0.z, d0.w + base0.w)),
                     fmaxf(fmaxf(d1.x + base1.x, d1.y + base1.y),
                           fmaxf(d1.z + base1.z, d1.w + base1.w)));
    float m3 = fmaxf(fmaxf(fmaxf(e0.x + base0.x, e0.y + base0.y),
                           fmaxf(e0.z + base0.z, e0.w + base0.w)),
                     fmaxf(fmaxf(e1.x + base1.x, e1.y + base1.y),
                           fmaxf(e1.z + base1.z, e1.w + base1.w)));

    // 4 independent wave-wide max reductions (interleave for ILP)
    #pragma unroll
    for (int off = 32; off > 0; off >>= 1) {
        m0 = fmaxf(m0, __shfl_down(m0, off, 64));
        m1 = fmaxf(m1, __shfl_down(m1, off, 64));
        m2 = fmaxf(m2, __shfl_down(m2, off, 64));
        m3 = fmaxf(m3, __shfl_down(m3, off, 64));
    }

    if (lane == 0) {
        s_add[w * 4 + 0] = m0;
        s_add[w * 4 + 1] = m1;
        s_add[w * 4 + 2] = m2;
        s_add[w * 4 + 3] = m3;
    }
    __syncthreads();

    if (t == 0) {
        float sum = 0.0f;
        #pragma unroll
        for (int i = 0; i < 16; ++i) sum += s_add[i];
        float mean = sum * (1.0f / 16.0f);
        float booster = fmaxf(0.5f, (2.0f - mean) * 0.5f);
        out[3 + b] = booster;
        // spread atomics over 256 slots to avoid same-address serialization
        atomicAdd(&accum[b & 255], weights[b] * sum);
    }
}

// Column sums over the first B rows of outputs. 256 blocks x 512 threads
// (was 64 blocks -> only 25% of CUs); coalesced (thread = bin).
__global__ void colsum_kernel(const float* __restrict__ outputs,
                              float* __restrict__ bcol,
                              int rows_per_block) {
    const int t = threadIdx.x;            // bin index, 0..511
    const int r0 = blockIdx.x * rows_per_block;
    float local = 0.0f;
    for (int r = 0; r < rows_per_block; ++r)
        local += outputs[(size_t)(r0 + r) * NBINS + t];
    atomicAdd(&bcol[t], local);
}

__global__ void final_kernel(const float* __restrict__ bcol,
                             const float* __restrict__ accum,
                             float* __restrict__ out,
                             float inv_count, float inv_target) {
    __shared__ float smax[NBINS];
    __shared__ float smin[NBINS];
    const int t = threadIdx.x;
    float v = bcol[t];
    smax[t] = v;
    smin[t] = v;
    __syncthreads();
    for (int s = NBINS / 2; s > 0; s >>= 1) {
        if (t < s) {
            smax[t] = fmaxf(smax[t], smax[t + s]);
            smin[t] = fminf(smin[t], smin[t + s]);
        }
        __syncthreads();
    }
    if (t == 0) {
        float acc = 0.0f;
        for (int i = 0; i < 256; ++i) acc += accum[i];
        float add_mean = acc * inv_count;
        float d = 2.0f - add_mean;
        float diff = d * d;
        float bn = (smax[0] - smin[0]) * inv_target;
        out[0] = bn + diff;
        out[1] = diff;
        out[2] = bn;
    }
}

extern "C" void kernel_launch(void* const* d_in, const int* in_sizes, int n_in,
                              void* d_out, int out_size, void* d_ws, size_t ws_size,
                              hipStream_t stream) {
    const float* outputs = (const float*)d_in[0];  // (N, 512)
    const float* y       = (const float*)d_in[1];  // (B, K) float-encoded indices
    const float* weights = (const float*)d_in[2];  // (B,)
    float* out = (float*)d_out;

    const int B = in_sizes[2];              // 8192
    const int K = in_sizes[1] / B;          // 16
    const int N = in_sizes[0] / NBINS;      // 100000

    float* ws    = (float*)d_ws;
    float* bcol  = ws;                      // 512 floats
    float* accum = ws + NBINS;              // 256 floats

    // ws is re-poisoned (0xAA) before every timed launch — zero it here.
    init_ws_kernel<<<1, 1024, 0, stream>>>(ws, NBINS + 256);

    // (K/4) waves of 64 threads per block; K=16 -> 256 threads
    main_kernel<<<B, (K / 4) * 64, 0, stream>>>(outputs, y, weights, out, accum, K);

    const int rows_per_block = 32;          // 256 blocks cover B=8192 rows
    colsum_kernel<<<B / rows_per_block, NBINS, 0, stream>>>(outputs, bcol, rows_per_block);

    final_kernel<<<1, NBINS, 0, stream>>>(bcol, accum, out,
                                          1.0f / (float)(B * K),
                                          (float)NBINS / (float)N);
}

// Round 2
// 290.942 us; speedup vs baseline: 1.1158x; 1.0283x over previous
//
#include <hip/hip_runtime.h>

#define NBINS 512
#define COL_BLOCKS 256

// Fused kernel, grid = B + COL_BLOCKS, 256 threads/block.
//
// Blocks [0, B): one block per batch row b. Wave w handles neighbors
//   k = 4w..4w+3. No LDS staging of the base row (4x intra-block reuse is
//   served by L1/L2; row is 2 KB). Each thread keeps 10 float4 loads in
//   flight. Result: booster -> out[3+b], weights[b]*sum -> ws[b] (plain
//   store, so no ws zero-init is needed despite the 0xAA poison).
//
// Blocks [B, B+COL_BLOCKS): column-sum partials over a 32-row chunk of the
//   first B rows; plain-store 512 partials per block into ws[B + c*512 ..].
//   These run CONCURRENTLY with the main blocks (they used to be a serial
//   dependent launch), hiding their 16.8 MB under the gather's BW shadow.
__global__ __launch_bounds__(256) void fused_kernel(
        const float* __restrict__ outputs,
        const float* __restrict__ y,
        const float* __restrict__ weights,
        float* __restrict__ out,          // d_out: [cost, diff, bnorm, booster(B)]
        float* __restrict__ ws,           // [0,B): wsum; [B, B+COL_BLOCKS*512): colsum partials
        int B, int K) {
    const int t = threadIdx.x;

    if ((int)blockIdx.x >= B) {
        // ---- column-sum path ----
        const int c = blockIdx.x - B;
        const int rows = B / COL_BLOCKS;          // 32
        const float* base = outputs + (size_t)c * rows * NBINS;
        float l0 = 0.0f, l1 = 0.0f;
        #pragma unroll 4
        for (int r = 0; r < rows; ++r) {
            l0 += base[(size_t)r * NBINS + t];
            l1 += base[(size_t)r * NBINS + t + 256];
        }
        float* dst = ws + B + (size_t)c * NBINS;
        dst[t] = l0;
        dst[t + 256] = l1;
        return;
    }

    // ---- main path ----
    __shared__ float s_add[16];

    const int b = blockIdx.x;
    const int w = t >> 6;        // wave id, 0..3
    const int lane = t & 63;

    // 4 neighbor indices for this wave (y >= 0, trunc == int cast)
    const float4 yv = ((const float4*)(y + (size_t)b * K))[w];
    const int nn0 = (int)yv.x;
    const int nn1 = (int)yv.y;
    const int nn2 = (int)yv.z;
    const int nn3 = (int)yv.w;

    const float4* bp = (const float4*)(outputs + (size_t)b * NBINS);
    const float4* r0 = (const float4*)(outputs + (size_t)nn0 * NBINS);
    const float4* r1 = (const float4*)(outputs + (size_t)nn1 * NBINS);
    const float4* r2 = (const float4*)(outputs + (size_t)nn2 * NBINS);
    const float4* r3 = (const float4*)(outputs + (size_t)nn3 * NBINS);

    const int i0 = lane * 2;
    const int i1 = lane * 2 + 1;

    // Issue all loads up front; compute afterwards.
    float4 base0 = bp[i0], base1 = bp[i1];
    float4 a0 = r0[i0], a1 = r0[i1];
    float4 c0 = r1[i0], c1 = r1[i1];
    float4 d0 = r2[i0], d1 = r2[i1];
    float4 e0 = r3[i0], e1 = r3[i1];

    float m0 = fmaxf(fmaxf(fmaxf(a0.x + base0.x, a0.y + base0.y),
                           fmaxf(a0.z + base0.z, a0.w + base0.w)),
                     fmaxf(fmaxf(a1.x + base1.x, a1.y + base1.y),
                           fmaxf(a1.z + base1.z, a1.w + base1.w)));
    float m1 = fmaxf(fmaxf(fmaxf(c0.x + base0.x, c0.y + base0.y),
                           fmaxf(c0.z + base0.z, c0.w + base0.w)),
                     fmaxf(fmaxf(c1.x + base1.x, c1.y + base1.y),
                           fmaxf(c1.z + base1.z, c1.w + base1.w)));
    float m2 = fmaxf(fmaxf(fmaxf(d0.x + base0.x, d0.y + base0.y),
                           fmaxf(d0.z + base0.z, d0.w + base0.w)),
                     fmaxf(fmaxf(d1.x + base1.x, d1.y + base1.y),
                           fmaxf(d1.z + base1.z, d1.w + base1.w)));
    float m3 = fmaxf(fmaxf(fmaxf(e0.x + base0.x, e0.y + base0.y),
                           fmaxf(e0.z + base0.z, e0.w + base0.w)),
                     fmaxf(fmaxf(e1.x + base1.x, e1.y + base1.y),
                           fmaxf(e1.z + base1.z, e1.w + base1.w)));

    // 4 independent wave-wide max reductions (interleaved for ILP)
    #pragma unroll
    for (int off = 32; off > 0; off >>= 1) {
        m0 = fmaxf(m0, __shfl_down(m0, off, 64));
        m1 = fmaxf(m1, __shfl_down(m1, off, 64));
        m2 = fmaxf(m2, __shfl_down(m2, off, 64));
        m3 = fmaxf(m3, __shfl_down(m3, off, 64));
    }

    if (lane == 0) {
        s_add[w * 4 + 0] = m0;
        s_add[w * 4 + 1] = m1;
        s_add[w * 4 + 2] = m2;
        s_add[w * 4 + 3] = m3;
    }
    __syncthreads();

    if (t == 0) {
        float sum = 0.0f;
        #pragma unroll
        for (int i = 0; i < 16; ++i) sum += s_add[i];
        float mean = sum * (1.0f / 16.0f);
        float booster = fmaxf(0.5f, (2.0f - mean) * 0.5f);
        out[3 + b] = booster;
        ws[b] = weights[b] * sum;   // plain store; reduced in final_kernel
    }
}

// Single 512-thread block: reduce B weighted sums, reduce COL_BLOCKS x 512
// colsum partials to bcol, min/max over bins, write out[0..2].
__global__ __launch_bounds__(512) void final_kernel(
        const float* __restrict__ ws,
        float* __restrict__ out,
        int B, float inv_count, float inv_target) {
    __shared__ float ssum[NBINS];
    __shared__ float smax[NBINS];
    __shared__ float smin[NBINS];
    const int t = threadIdx.x;

    // weighted-sum reduction over ws[0:B), coalesced stride-512
    float acc = 0.0f;
    #pragma unroll 4
    for (int j = t; j < B; j += NBINS)
        acc += ws[j];
    ssum[t] = acc;

    // bcol[t] = sum of COL_BLOCKS partials, coalesced across t
    const float* part = ws + B;
    float colv = 0.0f;
    #pragma unroll 8
    for (int c = 0; c < COL_BLOCKS; ++c)
        colv += part[(size_t)c * NBINS + t];
    smax[t] = colv;
    smin[t] = colv;
    __syncthreads();

    for (int s = NBINS / 2; s > 0; s >>= 1) {
        if (t < s) {
            ssum[t] += ssum[t + s];
            smax[t] = fmaxf(smax[t], smax[t + s]);
            smin[t] = fminf(smin[t], smin[t + s]);
        }
        __syncthreads();
    }
    if (t == 0) {
        float add_mean = ssum[0] * inv_count;
        float d = 2.0f - add_mean;
        float diff = d * d;
        float bn = (smax[0] - smin[0]) * inv_target;
        out[0] = bn + diff;
        out[1] = diff;
        out[2] = bn;
    }
}

extern "C" void kernel_launch(void* const* d_in, const int* in_sizes, int n_in,
                              void* d_out, int out_size, void* d_ws, size_t ws_size,
                              hipStream_t stream) {
    const float* outputs = (const float*)d_in[0];  // (N, 512)
    const float* y       = (const float*)d_in[1];  // (B, K) float-encoded indices
    const float* weights = (const float*)d_in[2];  // (B,)
    float* out = (float*)d_out;

    const int B = in_sizes[2];              // 8192
    const int K = in_sizes[1] / B;          // 16
    const int N = in_sizes[0] / NBINS;      // 100000

    float* ws = (float*)d_ws;

    fused_kernel<<<B + COL_BLOCKS, 256, 0, stream>>>(outputs, y, weights, out, ws, B, K);

    final_kernel<<<1, NBINS, 0, stream>>>(ws, out, B,
                                          1.0f / (float)(B * K),
                                          (float)NBINS / (float)N);
}